// Round 15
// baseline (1089.966 us; speedup 1.0000x reference)
//
#include <hip/hip_runtime.h>
#include <hip/hip_bf16.h>

#define NROWS 20000
#define IPI 128
#define OPI 64
#define OPO 16
#define BK 256
#define BK2 1024
#define A4S 10240           // padded fp4-A row stride (bytes), mult of 1024

typedef __attribute__((ext_vector_type(8))) short bf16x8;
typedef __attribute__((ext_vector_type(4))) float f32x4;
typedef __attribute__((ext_vector_type(2))) unsigned int u32x2;
typedef __attribute__((ext_vector_type(4))) unsigned int u32x4;

// fp4 LUT: nibble n -> e4m3 byte of value {0,.5,1,1.5,2,3,4,6}[n]
#define LUT_LO 0x3C383000u   // n=0..3 : 0x00,0x30,0x38,0x3C
#define LUT_HI 0x4C484440u   // n=4..7 : 0x40,0x44,0x48,0x4C

static __device__ __forceinline__ unsigned short f2bf(float f) {
    __hip_bfloat16 h = __float2bfloat16(f);           // RN
    return *reinterpret_cast<unsigned short*>(&h);
}
static __device__ __forceinline__ unsigned pk2(float a, float b) {
    return (unsigned)f2bf(a) | ((unsigned)f2bf(b) << 16);
}
static __device__ __forceinline__ unsigned pk4_fp8(float a, float b, float c, float d) {
    int v = __builtin_amdgcn_cvt_pk_fp8_f32(a, b, 0, false);
    v = __builtin_amdgcn_cvt_pk_fp8_f32(c, d, v, true);
    return (unsigned)v;
}
static __device__ __forceinline__ unsigned char f2fp8(float a) {
    return (unsigned char)(pk4_fp8(a, 0.f, 0.f, 0.f) & 0xff);
}
// quantize a in [0,1): nibble encodes value q=4a on levels {0,.5,..,2}∪{3,4}
static __device__ __forceinline__ unsigned nib4(float a) {
    const float q = a * 4.f;
    const float n = (q < 2.5f) ? fminf(rintf(q + q), 4.f)
                               : fminf(rintf(q), 4.f) + 2.f;
    return (unsigned)n;
}
// expand 8 nibbles (u32) -> 8 e4m3 bytes (u32x2), elements in order
static __device__ __forceinline__ u32x2 exp8(unsigned w) {
    const unsigned sl = w & 0x07070707u;          // n0,n2,n4,n6
    const unsigned sh = (w >> 4) & 0x07070707u;   // n1,n3,n5,n7
    const unsigned fe = __builtin_amdgcn_perm(LUT_HI, LUT_LO, sl);
    const unsigned fo = __builtin_amdgcn_perm(LUT_HI, LUT_LO, sh);
    u32x2 o;
    o[0] = __builtin_amdgcn_perm(fo, fe, 0x05010400u);   // e0,e1,e2,e3
    o[1] = __builtin_amdgcn_perm(fo, fe, 0x07030602u);   // e4,e5,e6,e7
    return o;
}

// ---------------- kernel 0: Bt = bf16((X @ W1)^T)  [64][N] ----------------
__global__ __launch_bounds__(256)
void k_xw1(const float* __restrict__ X, const float* __restrict__ W1,
           unsigned short* __restrict__ Bt) {
    __shared__ float w1[IPI * OPI];           // 32 KB
    const int t = threadIdx.x;
    for (int i = t * 4; i < IPI * OPI; i += 1024)
        *(float4*)&w1[i] = *(const float4*)&W1[i];
    __syncthreads();

    const int r  = blockIdx.x * 16 + (t >> 4);   // 1250*16 == 20000 exact
    const int c4 = (t & 15) * 4;
    const float* xr = X + (size_t)r * IPI;
    float4 acc = make_float4(0.f, 0.f, 0.f, 0.f);
    #pragma unroll 8
    for (int k = 0; k < IPI; ++k) {
        const float x = xr[k];
        const float4 w = *(const float4*)&w1[k * OPI + c4];
        acc.x = fmaf(x, w.x, acc.x);
        acc.y = fmaf(x, w.y, acc.y);
        acc.z = fmaf(x, w.z, acc.z);
        acc.w = fmaf(x, w.w, acc.w);
    }
    Bt[(size_t)(c4 + 0) * NROWS + r] = f2bf(acc.x);
    Bt[(size_t)(c4 + 1) * NROWS + r] = f2bf(acc.y);
    Bt[(size_t)(c4 + 2) * NROWS + r] = f2bf(acc.z);
    Bt[(size_t)(c4 + 3) * NROWS + r] = f2bf(acc.w);
}

// -------- k_gemm1: H[s] = bf16(A) @ bf16(B), tile 64x64, BK=256 ---------
// High-occupancy variant: A-only LDS (32 KB), B direct from L2-resident Bt,
// single-buffered; 4-5 blocks/CU provide the HBM overlap (m114 mechanism).
__global__ __launch_bounds__(256, 4)
void k_gemm1(const float* __restrict__ A, const unsigned short* __restrict__ Bt,
             float* __restrict__ Out, unsigned char* __restrict__ A4, int KC) {
    __shared__ unsigned short As[64 * BK];    // 32 KB [row][k], chunk-swizzled
    const int t    = threadIdx.x;
    const int lane = t & 63;
    const int wid  = t >> 6;
    const int lrow = lane & 15;
    const int lk   = lane >> 4;               // 0..3
    const int brow    = blockIdx.x * 64;
    const int k_begin = blockIdx.y * KC;
    const int k_end   = min(NROWS, k_begin + KC);   // multiple of 8

    const int sc_c = lane >> 1;               // chunk this lane writes
    const int sc_h = (lane & 1) * 4;          // half-chunk elem offset

    f32x4 acc[4];
    #pragma unroll
    for (int n = 0; n < 4; ++n) acc[n] = (f32x4){0.f, 0.f, 0.f, 0.f};

    for (int kt = k_begin; kt < k_end; kt += BK) {
        const int  kg  = kt + lane * 4;
        const bool kok = kg < k_end;          // k_end%4==0 -> float4 granule safe

        // ---- load A: 16 x 1KB bursts (one row each) ----
        f32x4 va[16];
        #pragma unroll
        for (int i = 0; i < 16; ++i) {
            const int grow = brow + wid * 16 + i;
            va[i] = (f32x4){0.f, 0.f, 0.f, 0.f};
            if (kok && grow < NROWS)
                va[i] = __builtin_nontemporal_load(
                    (const f32x4*)(A + (size_t)grow * NROWS + kg));
        }
        // ---- A4 fp4 copy (aligned 128B line per row-instr) ----
        #pragma unroll
        for (int i = 0; i < 16; ++i) {
            const int grow = brow + wid * 16 + i;
            if (kok && grow < NROWS) {
                const unsigned pk = nib4(va[i][0]) | (nib4(va[i][1]) << 4) |
                                    (nib4(va[i][2]) << 8) | (nib4(va[i][3]) << 12);
                *(unsigned short*)(A4 + (size_t)grow * A4S + (kg >> 1)) =
                    (unsigned short)pk;
            }
        }
        __syncthreads();                      // prev compute done reading As

        // ---- LDS write (regs -> swizzled As) ----
        #pragma unroll
        for (int i = 0; i < 16; ++i) {
            const int r = wid * 16 + i;
            u32x2 u;
            u[0] = pk2(va[i][0], va[i][1]);
            u[1] = pk2(va[i][2], va[i][3]);
            const int slot = (sc_c ^ (r & 7)) * 8 + sc_h;
            *(u32x2*)&As[r * BK + slot] = u;
        }
        __syncthreads();

        // ---- compute: A from LDS, B direct from L2-resident Bt ----
        #pragma unroll
        for (int h = 0; h < 8; ++h) {
            const int c  = h * 4 + lk;
            const int sc = (c & ~7) | ((c & 7) ^ (lrow & 7));
            const bf16x8 a = *(const bf16x8*)&As[(wid * 16 + lrow) * BK + sc * 8];
            const int kb = kt + c * 8;        // granule of 8 (k_end%8==0)
            #pragma unroll
            for (int n = 0; n < 4; ++n) {
                bf16x8 b = (bf16x8){0, 0, 0, 0, 0, 0, 0, 0};
                if (kb < k_end)
                    b = *(const bf16x8*)(Bt + (size_t)(n * 16 + lrow) * NROWS + kb);
                acc[n] = __builtin_amdgcn_mfma_f32_16x16x32_bf16(a, b, acc[n], 0, 0, 0);
            }
        }
    }

    // epilogue: D map col=lane&15, row=(lane>>4)*4+r  (verified, absmax 0)
    float* outp = Out + (size_t)blockIdx.y * NROWS * OPI;
    const int r0 = (lane >> 4) * 4;
    #pragma unroll
    for (int n = 0; n < 4; ++n)
        #pragma unroll
        for (int r = 0; r < 4; ++r) {
            const int grow = brow + wid * 16 + r0 + r;
            if (grow < NROWS)
                outp[(size_t)grow * OPI + n * 16 + lrow] = acc[n][r];
        }
}

// ------- k_hw2: Zt8 = fp8( (relu(sum_s H[s]) @ W2)^T / 4 )  [16][N] ------
__global__ __launch_bounds__(256)
void k_hw2(const float* __restrict__ Hpart, const float* __restrict__ W2,
           unsigned char* __restrict__ Zt8, int S1) {
    __shared__ float w2[OPI * OPO];
    __shared__ float hs[16 * 68];
    const int t = threadIdx.x;
    if (t * 4 < OPI * OPO)
        *(float4*)&w2[t * 4] = *(const float4*)&W2[t * 4];

    const int r  = t >> 4;
    const int c4 = (t & 15) * 4;
    const size_t rowg = (size_t)blockIdx.x * 16 + r;   // 1250*16 == 20000

    float4 h = make_float4(0.f, 0.f, 0.f, 0.f);
    for (int s = 0; s < S1; ++s) {
        const float4 v = *(const float4*)&Hpart[((size_t)s * NROWS + rowg) * OPI + c4];
        h.x += v.x; h.y += v.y; h.z += v.z; h.w += v.w;
    }
    hs[r * 68 + c4 + 0] = fmaxf(h.x, 0.f);
    hs[r * 68 + c4 + 1] = fmaxf(h.y, 0.f);
    hs[r * 68 + c4 + 2] = fmaxf(h.z, 0.f);
    hs[r * 68 + c4 + 3] = fmaxf(h.w, 0.f);
    __syncthreads();

    const int c = t & 15;
    float z = 0.f;
    #pragma unroll 8
    for (int k = 0; k < OPI; ++k)
        z = fmaf(hs[r * 68 + k], w2[k * OPO + c], z);
    Zt8[(size_t)c * NROWS + rowg] = f2fp8(z * 0.25f);   // /4; A4 carries x4
}

// -------- k_gemm2: L[s] = fp4(A)->fp8 @ Zt8^T, tile 64x16, BK2=1024 -----
__global__ __launch_bounds__(256)
void k_gemm2(const unsigned char* __restrict__ A4,
             const unsigned char* __restrict__ Zt8,
             float* __restrict__ Out, int KC) {
    __shared__ unsigned char As[64 * BK2];    // 64 KB fp8, 16B-chunk swizzled
    __shared__ unsigned char Bs[16 * BK2];    // 16 KB
    const int t    = threadIdx.x;
    const int lane = t & 63;
    const int wid  = t >> 6;
    const int lrow = lane & 15;
    const int lk   = lane >> 4;
    const int brow    = blockIdx.x * 64;
    const int k_begin = blockIdx.y * KC;
    const int k_end   = min(NROWS, k_begin + KC);   // mult of 16

    f32x4 acc = (f32x4){0.f, 0.f, 0.f, 0.f};

    const int zcol = t >> 4;
    const int zoff = (t & 15) * 64;

    u32x2 va[16], vna[16];                    // 8B nibbles = 16 elements/row
    u32x4 vz[4],  vnz[4];

    // prologue: load tile k_begin
    {
        const int  kgA = k_begin + lane * 16;           // element index
        const bool okA = kgA < k_end;
        #pragma unroll
        for (int i = 0; i < 16; ++i) {
            const int grow = brow + wid * 16 + i;
            va[i] = (u32x2){0u, 0u};
            if (okA && grow < NROWS)
                va[i] = *(const u32x2*)(A4 + (size_t)grow * A4S + (kgA >> 1));
        }
        #pragma unroll
        for (int j = 0; j < 4; ++j) {
            const int kg = k_begin + zoff + j * 16;
            vz[j] = (u32x4){0u, 0u, 0u, 0u};
            if (kg < k_end)
                vz[j] = *(const u32x4*)(Zt8 + (size_t)zcol * NROWS + kg);
        }
    }

    for (int kt = k_begin; kt < k_end; kt += BK2) {
        // ---- expand fp4 -> fp8 and write LDS ----
        #pragma unroll
        for (int i = 0; i < 16; ++i) {
            const int r  = wid * 16 + i;
            const int c  = lane;              // 16B chunk 0..63
            const int sc = (c & ~7) | ((c & 7) ^ (r & 7));
            u32x4 ex;
            const u32x2 e0 = exp8(va[i][0]);
            const u32x2 e1 = exp8(va[i][1]);
            ex[0] = e0[0]; ex[1] = e0[1]; ex[2] = e1[0]; ex[3] = e1[1];
            *(u32x4*)&As[r * BK2 + sc * 16] = ex;
        }
        #pragma unroll
        for (int j = 0; j < 4; ++j) {
            const int c  = (zoff >> 4) + j;
            const int sc = (c & ~7) | ((c & 7) ^ (zcol & 7));
            *(u32x4*)&Bs[zcol * BK2 + sc * 16] = vz[j];
        }
        __syncthreads();

        // ---- issue next-tile loads (overlap compute) ----
        {
            const int  kgn = kt + BK2 + lane * 16;
            const bool nok = kgn < k_end;
            #pragma unroll
            for (int i = 0; i < 16; ++i) {
                const int grow = brow + wid * 16 + i;
                vna[i] = (u32x2){0u, 0u};
                if (nok && grow < NROWS)
                    vna[i] = *(const u32x2*)(A4 + (size_t)grow * A4S + (kgn >> 1));
            }
            #pragma unroll
            for (int j = 0; j < 4; ++j) {
                const int kg = kt + BK2 + zoff + j * 16;
                vnz[j] = (u32x4){0u, 0u, 0u, 0u};
                if (kg < k_end)
                    vnz[j] = *(const u32x4*)(Zt8 + (size_t)zcol * NROWS + kg);
            }
        }

        // ---- compute ----
        #pragma unroll
        for (int h = 0; h < 32; ++h) {        // 32 x K=32
            const int k0   = h * 32 + lk * 8; // lane's 8 k-bytes
            const int c    = k0 >> 4;
            const int hb   = k0 & 15;         // 0 or 8
            const int sc   = (c & ~7) | ((c & 7) ^ (lrow & 7));
            const long long a = *(const long long*)&As[(wid * 16 + lrow) * BK2 + sc * 16 + hb];
            const long long b = *(const long long*)&Bs[lrow * BK2 + sc * 16 + hb];
            acc = __builtin_amdgcn_mfma_f32_16x16x32_fp8_fp8(a, b, acc, 0, 0, 0);
        }
        __syncthreads();

        #pragma unroll
        for (int i = 0; i < 16; ++i) va[i] = vna[i];
        #pragma unroll
        for (int j = 0; j < 4; ++j)  vz[j] = vnz[j];
    }

    float* outp = Out + (size_t)blockIdx.y * NROWS * OPO;
    const int r0 = (lane >> 4) * 4;
    #pragma unroll
    for (int r = 0; r < 4; ++r) {
        const int grow = brow + wid * 16 + r0 + r;
        if (grow < NROWS) outp[(size_t)grow * OPO + lrow] = acc[r];
    }
}

// ---- k_softmax: out = softmax(sum_s Lpart[s])  (x4/÷4 scales cancel) ----
__global__ __launch_bounds__(256)
void k_softmax(const float* __restrict__ Lpart, float* __restrict__ out, int S2) {
    const int t = threadIdx.x;
    const size_t base = (size_t)blockIdx.x * 256;      // 16 rows x 16 cols
    float v = 0.f;
    for (int s = 0; s < S2; ++s)
        v += Lpart[(size_t)s * NROWS * OPO + base + t];
    float m = v;
    #pragma unroll
    for (int d = 8; d >= 1; d >>= 1) m = fmaxf(m, __shfl_xor(m, d, 16));
    const float e = expf(v - m);
    float sum = e;
    #pragma unroll
    for (int d = 8; d >= 1; d >>= 1) sum += __shfl_xor(sum, d, 16);
    out[base + t] = e / sum;
}

// ------------------------------------------------------------------------
extern "C" void kernel_launch(void* const* d_in, const int* in_sizes, int n_in,
                              void* d_out, int out_size, void* d_ws, size_t ws_size,
                              hipStream_t stream) {
    const float* A  = (const float*)d_in[0];
    const float* X  = (const float*)d_in[1];
    const float* W1 = (const float*)d_in[2];
    const float* W2 = (const float*)d_in[3];
    float* out = (float*)d_out;

    auto al = [](size_t x) { return (x + 1023) & ~(size_t)1023; };
    const size_t a4_b = al((size_t)NROWS * A4S);          // 205 MB fp4 A (padded)
    const size_t bt_b = al((size_t)OPI * NROWS * 2);
    const size_t z8_b = al((size_t)OPO * NROWS);

    int S1 = 8, S2 = 8;
    auto need = [&](int s1, int s2) {
        return a4_b + bt_b + z8_b +
               ((size_t)s1 * NROWS * OPI + (size_t)s2 * NROWS * OPO) * sizeof(float);
    };
    while ((S1 > 1 || S2 > 1) && need(S1, S2) > ws_size) {
        if (S1 > 1) S1 >>= 1;
        if (S2 > 1) S2 >>= 1;
    }

    char* p = (char*)d_ws;
    unsigned char*  A4  = (unsigned char*)p;
    unsigned short* Bt  = (unsigned short*)(p + a4_b);
    unsigned char*  Zt8 = (unsigned char*)(p + a4_b + bt_b);
    float* H = (float*)(p + a4_b + bt_b + z8_b);        // [S1][N][64]
    float* L = H + (size_t)S1 * NROWS * OPI;            // [S2][N][16]

    const int MT  = (NROWS + 63) / 64;                  // 313
    const int KC1 = ((((NROWS + S1 - 1) / S1) + BK - 1) / BK) * BK;
    const int KC2 = ((((NROWS + S2 - 1) / S2) + 511) & ~511);   // 2560

    k_xw1<<<dim3(NROWS / 16), 256, 0, stream>>>(X, W1, Bt);
    k_gemm1<<<dim3(MT, S1), 256, 0, stream>>>(A, Bt, H, A4, KC1);
    k_hw2<<<dim3(NROWS / 16), 256, 0, stream>>>(H, W2, Zt8, S1);
    k_gemm2<<<dim3(MT, S2), 256, 0, stream>>>(A4, Zt8, L, KC2);
    k_softmax<<<dim3(NROWS * OPO / 256), 256, 0, stream>>>(L, out, S2);
}

// Round 16
// 858.970 us; speedup vs baseline: 1.2689x; 1.2689x over previous
//
#include <hip/hip_runtime.h>
#include <hip/hip_bf16.h>

#define NROWS 20000
#define IPI 128
#define OPI 64
#define OPO 16
#define BK 256
#define BK2 1024
#define A4S 10240           // padded fp4-A row stride (bytes), mult of 1024

typedef __attribute__((ext_vector_type(4))) float f32x4;
typedef __attribute__((ext_vector_type(2))) unsigned int u32x2;
typedef __attribute__((ext_vector_type(4))) unsigned int u32x4;

// fp4 LUT: nibble n -> e4m3 byte of value {0,.5,1,1.5,2,3,4,6}[n]
#define LUT_LO 0x3C383000u   // n=0..3 : 0x00,0x30,0x38,0x3C
#define LUT_HI 0x4C484440u   // n=4..7 : 0x40,0x44,0x48,0x4C

static __device__ __forceinline__ unsigned pk4_fp8(float a, float b, float c, float d) {
    int v = __builtin_amdgcn_cvt_pk_fp8_f32(a, b, 0, false);
    v = __builtin_amdgcn_cvt_pk_fp8_f32(c, d, v, true);
    return (unsigned)v;
}
static __device__ __forceinline__ unsigned char f2fp8(float a) {
    return (unsigned char)(pk4_fp8(a, 0.f, 0.f, 0.f) & 0xff);
}
// quantize a in [0,1): nibble encodes value q=4a on levels {0,.5,..,2}∪{3,4}
static __device__ __forceinline__ unsigned nib4(float a) {
    const float q = a * 4.f;
    const float n = (q < 2.5f) ? fminf(rintf(q + q), 4.f)
                               : fminf(rintf(q), 4.f) + 2.f;
    return (unsigned)n;
}
// expand 8 nibbles (u32) -> 8 e4m3 bytes (u32x2), elements in order
static __device__ __forceinline__ u32x2 exp8(unsigned w) {
    const unsigned sl = w & 0x07070707u;          // n0,n2,n4,n6
    const unsigned sh = (w >> 4) & 0x07070707u;   // n1,n3,n5,n7
    const unsigned fe = __builtin_amdgcn_perm(LUT_HI, LUT_LO, sl);
    const unsigned fo = __builtin_amdgcn_perm(LUT_HI, LUT_LO, sh);
    u32x2 o;
    o[0] = __builtin_amdgcn_perm(fo, fe, 0x05010400u);   // e0,e1,e2,e3
    o[1] = __builtin_amdgcn_perm(fo, fe, 0x07030602u);   // e4,e5,e6,e7
    return o;
}

// ---------------- kernel 0: Bt8 = fp8((X @ W1)^T)  [64][N] ----------------
__global__ __launch_bounds__(256)
void k_xw1(const float* __restrict__ X, const float* __restrict__ W1,
           unsigned char* __restrict__ Bt8) {
    __shared__ float w1[IPI * OPI];           // 32 KB
    const int t = threadIdx.x;
    for (int i = t * 4; i < IPI * OPI; i += 1024)
        *(float4*)&w1[i] = *(const float4*)&W1[i];
    __syncthreads();

    const int r  = blockIdx.x * 16 + (t >> 4);   // 1250*16 == 20000 exact
    const int c4 = (t & 15) * 4;
    const float* xr = X + (size_t)r * IPI;
    float4 acc = make_float4(0.f, 0.f, 0.f, 0.f);
    #pragma unroll 8
    for (int k = 0; k < IPI; ++k) {
        const float x = xr[k];
        const float4 w = *(const float4*)&w1[k * OPI + c4];
        acc.x = fmaf(x, w.x, acc.x);
        acc.y = fmaf(x, w.y, acc.y);
        acc.z = fmaf(x, w.z, acc.z);
        acc.w = fmaf(x, w.w, acc.w);
    }
    Bt8[(size_t)(c4 + 0) * NROWS + r] = f2fp8(acc.x);
    Bt8[(size_t)(c4 + 1) * NROWS + r] = f2fp8(acc.y);
    Bt8[(size_t)(c4 + 2) * NROWS + r] = f2fp8(acc.z);
    Bt8[(size_t)(c4 + 3) * NROWS + r] = f2fp8(acc.w);
}

// -------- k_gemm1: H[s] = fp8(A) @ fp8(B), tile 64x64, BK=256 -----------
// All-fp8 LDS (16+16 KB) -> 4-5 blocks/CU; 1KB A bursts; emits A4 nibbles.
__global__ __launch_bounds__(256, 4)
void k_gemm1(const float* __restrict__ A, const unsigned char* __restrict__ Bt8,
             float* __restrict__ Out, unsigned char* __restrict__ A4, int KC) {
    __shared__ unsigned char As[64 * BK];     // 16 KB fp8 [row][k], 16B-chunk swz
    __shared__ unsigned char Bs[64 * BK];     // 16 KB fp8 [col][k]
    const int t    = threadIdx.x;
    const int lane = t & 63;
    const int wid  = t >> 6;
    const int lrow = lane & 15;
    const int lk   = lane >> 4;               // 0..3
    const int brow    = blockIdx.x * 64;
    const int k_begin = blockIdx.y * KC;
    const int k_end   = min(NROWS, k_begin + KC);   // multiple of 4

    const int sc_c = lane >> 2;               // 16B chunk 0..15 this lane covers
    const int sc_b = (lane & 3) * 4;          // byte offset in chunk

    f32x4 acc[4];
    #pragma unroll
    for (int n = 0; n < 4; ++n) acc[n] = (f32x4){0.f, 0.f, 0.f, 0.f};

    for (int kt = k_begin; kt < k_end; kt += BK) {
        const int  kg  = kt + lane * 4;
        const bool kok = kg < k_end;          // k_end%4==0 -> 4-elem granule safe

        // ---- load A: 16 x 1KB bursts (one row each); B: 16 x 256B bursts ----
        f32x4    va[16];
        unsigned vbp[16];
        #pragma unroll
        for (int i = 0; i < 16; ++i) {
            const int grow = brow + wid * 16 + i;
            va[i] = (f32x4){0.f, 0.f, 0.f, 0.f};
            if (kok && grow < NROWS)
                va[i] = __builtin_nontemporal_load(
                    (const f32x4*)(A + (size_t)grow * NROWS + kg));
            vbp[i] = 0u;
            if (kok)
                vbp[i] = *(const unsigned*)(Bt8 + (size_t)(wid * 16 + i) * NROWS + kg);
        }
        // ---- A4 fp4 copy (2B per lane -> 128B aligned line per row-instr) ----
        #pragma unroll
        for (int i = 0; i < 16; ++i) {
            const int grow = brow + wid * 16 + i;
            if (kok && grow < NROWS) {
                const unsigned pk = nib4(va[i][0]) | (nib4(va[i][1]) << 4) |
                                    (nib4(va[i][2]) << 8) | (nib4(va[i][3]) << 12);
                *(unsigned short*)(A4 + (size_t)grow * A4S + (kg >> 1)) =
                    (unsigned short)pk;
            }
        }
        __syncthreads();                      // prev compute done reading LDS

        // ---- pack fp8 + LDS write (swizzled u32 per lane per row/col) ----
        #pragma unroll
        for (int i = 0; i < 16; ++i) {
            const int r  = wid * 16 + i;
            const int sc = (sc_c & ~7) | ((sc_c & 7) ^ (r & 7));
            *(unsigned*)&As[r * BK + sc * 16 + sc_b] =
                pk4_fp8(va[i][0], va[i][1], va[i][2], va[i][3]);
            *(unsigned*)&Bs[r * BK + sc * 16 + sc_b] = vbp[i];
        }
        __syncthreads();

        // ---- compute: 8 x K=32 fp8 MFMA ----
        #pragma unroll
        for (int h = 0; h < 8; ++h) {
            const int k0 = h * 32 + lk * 8;   // byte==elem offset in row
            const int c  = k0 >> 4;
            const int hb = k0 & 15;           // 0 or 8
            const int sc = (c & ~7) | ((c & 7) ^ (lrow & 7));
            const long long a =
                *(const long long*)&As[(wid * 16 + lrow) * BK + sc * 16 + hb];
            #pragma unroll
            for (int n = 0; n < 4; ++n) {
                const long long b =
                    *(const long long*)&Bs[(n * 16 + lrow) * BK + sc * 16 + hb];
                acc[n] = __builtin_amdgcn_mfma_f32_16x16x32_fp8_fp8(a, b, acc[n], 0, 0, 0);
            }
        }
    }

    // epilogue: D map col=lane&15, row=(lane>>4)*4+r  (verified, absmax 0)
    float* outp = Out + (size_t)blockIdx.y * NROWS * OPI;
    const int r0 = (lane >> 4) * 4;
    #pragma unroll
    for (int n = 0; n < 4; ++n)
        #pragma unroll
        for (int r = 0; r < 4; ++r) {
            const int grow = brow + wid * 16 + r0 + r;
            if (grow < NROWS)
                outp[(size_t)grow * OPI + n * 16 + lrow] = acc[n][r];
        }
}

// ------- k_hw2: Zt8 = fp8( (relu(sum_s H[s]) @ W2)^T / 4 )  [16][N] ------
__global__ __launch_bounds__(256)
void k_hw2(const float* __restrict__ Hpart, const float* __restrict__ W2,
           unsigned char* __restrict__ Zt8, int S1) {
    __shared__ float w2[OPI * OPO];
    __shared__ float hs[16 * 68];
    const int t = threadIdx.x;
    if (t * 4 < OPI * OPO)
        *(float4*)&w2[t * 4] = *(const float4*)&W2[t * 4];

    const int r  = t >> 4;
    const int c4 = (t & 15) * 4;
    const size_t rowg = (size_t)blockIdx.x * 16 + r;   // 1250*16 == 20000

    float4 h = make_float4(0.f, 0.f, 0.f, 0.f);
    for (int s = 0; s < S1; ++s) {
        const float4 v = *(const float4*)&Hpart[((size_t)s * NROWS + rowg) * OPI + c4];
        h.x += v.x; h.y += v.y; h.z += v.z; h.w += v.w;
    }
    hs[r * 68 + c4 + 0] = fmaxf(h.x, 0.f);
    hs[r * 68 + c4 + 1] = fmaxf(h.y, 0.f);
    hs[r * 68 + c4 + 2] = fmaxf(h.z, 0.f);
    hs[r * 68 + c4 + 3] = fmaxf(h.w, 0.f);
    __syncthreads();

    const int c = t & 15;
    float z = 0.f;
    #pragma unroll 8
    for (int k = 0; k < OPI; ++k)
        z = fmaf(hs[r * 68 + k], w2[k * OPO + c], z);
    Zt8[(size_t)c * NROWS + rowg] = f2fp8(z * 0.25f);   // /4; A4 carries x4
}

// -------- k_gemm2: L[s] = fp4(A)->fp8 @ Zt8^T, tile 64x16, BK2=1024 -----
__global__ __launch_bounds__(256)
void k_gemm2(const unsigned char* __restrict__ A4,
             const unsigned char* __restrict__ Zt8,
             float* __restrict__ Out, int KC) {
    __shared__ unsigned char As[64 * BK2];    // 64 KB fp8, 16B-chunk swizzled
    __shared__ unsigned char Bs[16 * BK2];    // 16 KB
    const int t    = threadIdx.x;
    const int lane = t & 63;
    const int wid  = t >> 6;
    const int lrow = lane & 15;
    const int lk   = lane >> 4;
    const int brow    = blockIdx.x * 64;
    const int k_begin = blockIdx.y * KC;
    const int k_end   = min(NROWS, k_begin + KC);   // mult of 16

    f32x4 acc = (f32x4){0.f, 0.f, 0.f, 0.f};

    const int zcol = t >> 4;
    const int zoff = (t & 15) * 64;

    u32x2 va[16], vna[16];                    // 8B nibbles = 16 elements/row
    u32x4 vz[4],  vnz[4];

    // prologue: load tile k_begin
    {
        const int  kgA = k_begin + lane * 16;           // element index
        const bool okA = kgA < k_end;
        #pragma unroll
        for (int i = 0; i < 16; ++i) {
            const int grow = brow + wid * 16 + i;
            va[i] = (u32x2){0u, 0u};
            if (okA && grow < NROWS)
                va[i] = *(const u32x2*)(A4 + (size_t)grow * A4S + (kgA >> 1));
        }
        #pragma unroll
        for (int j = 0; j < 4; ++j) {
            const int kg = k_begin + zoff + j * 16;
            vz[j] = (u32x4){0u, 0u, 0u, 0u};
            if (kg < k_end)
                vz[j] = *(const u32x4*)(Zt8 + (size_t)zcol * NROWS + kg);
        }
    }

    for (int kt = k_begin; kt < k_end; kt += BK2) {
        // ---- expand fp4 -> fp8 and write LDS ----
        #pragma unroll
        for (int i = 0; i < 16; ++i) {
            const int r  = wid * 16 + i;
            const int c  = lane;              // 16B chunk 0..63
            const int sc = (c & ~7) | ((c & 7) ^ (r & 7));
            u32x4 ex;
            const u32x2 e0 = exp8(va[i][0]);
            const u32x2 e1 = exp8(va[i][1]);
            ex[0] = e0[0]; ex[1] = e0[1]; ex[2] = e1[0]; ex[3] = e1[1];
            *(u32x4*)&As[r * BK2 + sc * 16] = ex;
        }
        #pragma unroll
        for (int j = 0; j < 4; ++j) {
            const int c  = (zoff >> 4) + j;
            const int sc = (c & ~7) | ((c & 7) ^ (zcol & 7));
            *(u32x4*)&Bs[zcol * BK2 + sc * 16] = vz[j];
        }
        __syncthreads();

        // ---- issue next-tile loads (overlap compute) ----
        {
            const int  kgn = kt + BK2 + lane * 16;
            const bool nok = kgn < k_end;
            #pragma unroll
            for (int i = 0; i < 16; ++i) {
                const int grow = brow + wid * 16 + i;
                vna[i] = (u32x2){0u, 0u};
                if (nok && grow < NROWS)
                    vna[i] = *(const u32x2*)(A4 + (size_t)grow * A4S + (kgn >> 1));
            }
            #pragma unroll
            for (int j = 0; j < 4; ++j) {
                const int kg = kt + BK2 + zoff + j * 16;
                vnz[j] = (u32x4){0u, 0u, 0u, 0u};
                if (kg < k_end)
                    vnz[j] = *(const u32x4*)(Zt8 + (size_t)zcol * NROWS + kg);
            }
        }

        // ---- compute ----
        #pragma unroll
        for (int h = 0; h < 32; ++h) {        // 32 x K=32
            const int k0   = h * 32 + lk * 8; // lane's 8 k-bytes
            const int c    = k0 >> 4;
            const int hb   = k0 & 15;         // 0 or 8
            const int sc   = (c & ~7) | ((c & 7) ^ (lrow & 7));
            const long long a = *(const long long*)&As[(wid * 16 + lrow) * BK2 + sc * 16 + hb];
            const long long b = *(const long long*)&Bs[lrow * BK2 + sc * 16 + hb];
            acc = __builtin_amdgcn_mfma_f32_16x16x32_fp8_fp8(a, b, acc, 0, 0, 0);
        }
        __syncthreads();

        #pragma unroll
        for (int i = 0; i < 16; ++i) va[i] = vna[i];
        #pragma unroll
        for (int j = 0; j < 4; ++j)  vz[j] = vnz[j];
    }

    float* outp = Out + (size_t)blockIdx.y * NROWS * OPO;
    const int r0 = (lane >> 4) * 4;
    #pragma unroll
    for (int r = 0; r < 4; ++r) {
        const int grow = brow + wid * 16 + r0 + r;
        if (grow < NROWS) outp[(size_t)grow * OPO + lrow] = acc[r];
    }
}

// ---- k_softmax: out = softmax(sum_s Lpart[s])  (x4/÷4 scales cancel) ----
__global__ __launch_bounds__(256)
void k_softmax(const float* __restrict__ Lpart, float* __restrict__ out, int S2) {
    const int t = threadIdx.x;
    const size_t base = (size_t)blockIdx.x * 256;      // 16 rows x 16 cols
    float v = 0.f;
    for (int s = 0; s < S2; ++s)
        v += Lpart[(size_t)s * NROWS * OPO + base + t];
    float m = v;
    #pragma unroll
    for (int d = 8; d >= 1; d >>= 1) m = fmaxf(m, __shfl_xor(m, d, 16));
    const float e = expf(v - m);
    float sum = e;
    #pragma unroll
    for (int d = 8; d >= 1; d >>= 1) sum += __shfl_xor(sum, d, 16);
    out[base + t] = e / sum;
}

// ------------------------------------------------------------------------
extern "C" void kernel_launch(void* const* d_in, const int* in_sizes, int n_in,
                              void* d_out, int out_size, void* d_ws, size_t ws_size,
                              hipStream_t stream) {
    const float* A  = (const float*)d_in[0];
    const float* X  = (const float*)d_in[1];
    const float* W1 = (const float*)d_in[2];
    const float* W2 = (const float*)d_in[3];
    float* out = (float*)d_out;

    auto al = [](size_t x) { return (x + 1023) & ~(size_t)1023; };
    const size_t a4_b = al((size_t)NROWS * A4S);          // 205 MB fp4 A (padded)
    const size_t bt_b = al((size_t)OPI * NROWS);          // fp8 Bt
    const size_t z8_b = al((size_t)OPO * NROWS);

    int S1 = 16, S2 = 8;
    auto need = [&](int s1, int s2) {
        return a4_b + bt_b + z8_b +
               ((size_t)s1 * NROWS * OPI + (size_t)s2 * NROWS * OPO) * sizeof(float);
    };
    while ((S1 > 1 || S2 > 1) && need(S1, S2) > ws_size) {
        if (S1 > 1) S1 >>= 1;
        if (S2 > 1) S2 >>= 1;
    }

    char* p = (char*)d_ws;
    unsigned char* A4  = (unsigned char*)p;
    unsigned char* Bt8 = (unsigned char*)(p + a4_b);
    unsigned char* Zt8 = (unsigned char*)(p + a4_b + bt_b);
    float* H = (float*)(p + a4_b + bt_b + z8_b);        // [S1][N][64]
    float* L = H + (size_t)S1 * NROWS * OPI;            // [S2][N][16]

    const int MT  = (NROWS + 63) / 64;                  // 313
    const int KC1 = ((((NROWS + S1 - 1) / S1) + BK - 1) / BK) * BK;
    const int KC2 = ((((NROWS + S2 - 1) / S2) + 511) & ~511);   // 2560

    k_xw1<<<dim3(NROWS / 16), 256, 0, stream>>>(X, W1, Bt8);
    k_gemm1<<<dim3(MT, S1), 256, 0, stream>>>(A, Bt8, H, A4, KC1);
    k_hw2<<<dim3(NROWS / 16), 256, 0, stream>>>(H, W2, Zt8, S1);
    k_gemm2<<<dim3(MT, S2), 256, 0, stream>>>(A4, Zt8, L, KC2);
    k_softmax<<<dim3(NROWS * OPO / 256), 256, 0, stream>>>(L, out, S2);
}

// Round 17
// 516.991 us; speedup vs baseline: 2.1083x; 1.6615x over previous
//
#include <hip/hip_runtime.h>
#include <hip/hip_bf16.h>

#define NROWS 20000
#define IPI 128
#define OPI 64
#define OPO 16
#define BK 256
#define BK2 1024
#define A4S 10240           // padded fp4-A row stride (bytes), mult of 1024

typedef __attribute__((ext_vector_type(8))) short bf16x8;
typedef __attribute__((ext_vector_type(4))) float f32x4;
typedef __attribute__((ext_vector_type(2))) unsigned int u32x2;
typedef __attribute__((ext_vector_type(4))) unsigned int u32x4;

// fp4 LUT: nibble n -> e4m3 byte of value {0,.5,1,1.5,2,3,4,6}[n]
#define LUT_LO 0x3C383000u   // n=0..3 : 0x00,0x30,0x38,0x3C
#define LUT_HI 0x4C484440u   // n=4..7 : 0x40,0x44,0x48,0x4C

static __device__ __forceinline__ unsigned short f2bf(float f) {
    __hip_bfloat16 h = __float2bfloat16(f);           // RN
    return *reinterpret_cast<unsigned short*>(&h);
}
static __device__ __forceinline__ unsigned pk2(float a, float b) {
    return (unsigned)f2bf(a) | ((unsigned)f2bf(b) << 16);
}
static __device__ __forceinline__ unsigned pk4_fp8(float a, float b, float c, float d) {
    int v = __builtin_amdgcn_cvt_pk_fp8_f32(a, b, 0, false);
    v = __builtin_amdgcn_cvt_pk_fp8_f32(c, d, v, true);
    return (unsigned)v;
}
static __device__ __forceinline__ unsigned char f2fp8(float a) {
    return (unsigned char)(pk4_fp8(a, 0.f, 0.f, 0.f) & 0xff);
}
// quantize a in [0,1): nibble encodes value q=4a on levels {0,.5,..,2}∪{3,4}
static __device__ __forceinline__ unsigned nib4(float a) {
    const float q = a * 4.f;
    const float n = (q < 2.5f) ? fminf(rintf(q + q), 4.f)
                               : fminf(rintf(q), 4.f) + 2.f;
    return (unsigned)n;
}
// expand 8 nibbles (u32) -> 8 e4m3 bytes (u32x2), elements in order
static __device__ __forceinline__ u32x2 exp8(unsigned w) {
    const unsigned sl = w & 0x07070707u;          // n0,n2,n4,n6
    const unsigned sh = (w >> 4) & 0x07070707u;   // n1,n3,n5,n7
    const unsigned fe = __builtin_amdgcn_perm(LUT_HI, LUT_LO, sl);
    const unsigned fo = __builtin_amdgcn_perm(LUT_HI, LUT_LO, sh);
    u32x2 o;
    o[0] = __builtin_amdgcn_perm(fo, fe, 0x05010400u);   // e0,e1,e2,e3
    o[1] = __builtin_amdgcn_perm(fo, fe, 0x07030602u);   // e4,e5,e6,e7
    return o;
}

// ---------------- kernel 0: Bt = bf16((X @ W1)^T)  [64][N] ----------------
__global__ __launch_bounds__(256)
void k_xw1(const float* __restrict__ X, const float* __restrict__ W1,
           unsigned short* __restrict__ Bt) {
    __shared__ float w1[IPI * OPI];           // 32 KB
    const int t = threadIdx.x;
    for (int i = t * 4; i < IPI * OPI; i += 1024)
        *(float4*)&w1[i] = *(const float4*)&W1[i];
    __syncthreads();

    const int r  = blockIdx.x * 16 + (t >> 4);   // 1250*16 == 20000 exact
    const int c4 = (t & 15) * 4;
    const float* xr = X + (size_t)r * IPI;
    float4 acc = make_float4(0.f, 0.f, 0.f, 0.f);
    #pragma unroll 8
    for (int k = 0; k < IPI; ++k) {
        const float x = xr[k];
        const float4 w = *(const float4*)&w1[k * OPI + c4];
        acc.x = fmaf(x, w.x, acc.x);
        acc.y = fmaf(x, w.y, acc.y);
        acc.z = fmaf(x, w.z, acc.z);
        acc.w = fmaf(x, w.w, acc.w);
    }
    Bt[(size_t)(c4 + 0) * NROWS + r] = f2bf(acc.x);
    Bt[(size_t)(c4 + 1) * NROWS + r] = f2bf(acc.y);
    Bt[(size_t)(c4 + 2) * NROWS + r] = f2bf(acc.z);
    Bt[(size_t)(c4 + 3) * NROWS + r] = f2bf(acc.w);
}

// -------- k_gemm1: H[s] = bf16(A) @ bf16(B), tile 64x64, BK=256 ---------
// T14 pipeline; emits A4 = fp4(4*A) nibbles, padded stride A4S.
__global__ __launch_bounds__(256)
void k_gemm1(const float* __restrict__ A, const unsigned short* __restrict__ Bt,
             float* __restrict__ Out, unsigned char* __restrict__ A4, int KC) {
    __shared__ unsigned short As[64 * BK];    // 32 KB [row][k], chunk-swizzled
    __shared__ unsigned short Bs[64 * BK];    // 32 KB [col][k], chunk-swizzled
    const int t    = threadIdx.x;
    const int lane = t & 63;
    const int wid  = t >> 6;
    const int lrow = lane & 15;
    const int lk   = lane >> 4;               // 0..3
    const int brow    = blockIdx.x * 64;
    const int k_begin = blockIdx.y * KC;
    const int k_end   = min(NROWS, k_begin + KC);   // multiple of 4

    const int sc_c = lane >> 1;               // chunk this lane writes
    const int sc_h = (lane & 1) * 4;          // half-chunk elem offset

    f32x4 acc[4];
    #pragma unroll
    for (int n = 0; n < 4; ++n) acc[n] = (f32x4){0.f, 0.f, 0.f, 0.f};

    f32x4 va[16], vna[16];
    u32x2 vb[16], vnb[16];

    // prologue: load tile k_begin
    {
        const int  kg  = k_begin + lane * 4;
        const bool kok = kg < k_end;
        #pragma unroll
        for (int i = 0; i < 16; ++i) {
            const int grow = brow + wid * 16 + i;
            va[i] = (f32x4){0.f, 0.f, 0.f, 0.f};
            if (kok && grow < NROWS)
                va[i] = __builtin_nontemporal_load(
                    (const f32x4*)(A + (size_t)grow * NROWS + kg));
            vb[i] = (u32x2){0u, 0u};
            if (kok)
                vb[i] = *(const u32x2*)(Bt + (size_t)(wid * 16 + i) * NROWS + kg);
        }
    }

    for (int kt = k_begin; kt < k_end; kt += BK) {
        // ---- LDS write phase (regs -> swizzled LDS) ----
        #pragma unroll
        for (int i = 0; i < 16; ++i) {
            const int r = wid * 16 + i;
            u32x2 u;
            u[0] = pk2(va[i][0], va[i][1]);
            u[1] = pk2(va[i][2], va[i][3]);
            const int slot = (sc_c ^ (r & 7)) * 8 + sc_h;
            *(u32x2*)&As[r * BK + slot] = u;
            *(u32x2*)&Bs[r * BK + slot] = vb[i];
        }
        __syncthreads();

        // ---- issue next-tile loads + this-tile A4 stores (overlap compute) ----
        {
            const int  kgn  = kt + BK + lane * 4;
            const bool nok  = kgn < k_end;
            #pragma unroll
            for (int i = 0; i < 16; ++i) {
                const int grow = brow + wid * 16 + i;
                vna[i] = (f32x4){0.f, 0.f, 0.f, 0.f};
                if (nok && grow < NROWS)
                    vna[i] = __builtin_nontemporal_load(
                        (const f32x4*)(A + (size_t)grow * NROWS + kgn));
                vnb[i] = (u32x2){0u, 0u};
                if (nok)
                    vnb[i] = *(const u32x2*)(Bt + (size_t)(wid * 16 + i) * NROWS + kgn);
            }
            const int  kg  = kt + lane * 4;
            const bool kok = kg < k_end;
            #pragma unroll
            for (int i = 0; i < 16; ++i) {
                const int grow = brow + wid * 16 + i;
                if (kok && grow < NROWS) {
                    const unsigned pk = nib4(va[i][0]) | (nib4(va[i][1]) << 4) |
                                        (nib4(va[i][2]) << 8) | (nib4(va[i][3]) << 12);
                    *(unsigned short*)(A4 + (size_t)grow * A4S + (kg >> 1)) =
                        (unsigned short)pk;
                }
            }
        }

        // ---- compute from LDS ----
        #pragma unroll
        for (int h = 0; h < 8; ++h) {
            const int c  = h * 4 + lk;
            const int sc = (c & ~7) | ((c & 7) ^ (lrow & 7));
            const bf16x8 a = *(const bf16x8*)&As[(wid * 16 + lrow) * BK + sc * 8];
            #pragma unroll
            for (int n = 0; n < 4; ++n) {
                const bf16x8 b = *(const bf16x8*)&Bs[(n * 16 + lrow) * BK + sc * 8];
                acc[n] = __builtin_amdgcn_mfma_f32_16x16x32_bf16(a, b, acc[n], 0, 0, 0);
            }
        }
        __syncthreads();

        #pragma unroll
        for (int i = 0; i < 16; ++i) { va[i] = vna[i]; vb[i] = vnb[i]; }
    }

    // epilogue: D map col=lane&15, row=(lane>>4)*4+r  (verified, absmax 0)
    float* outp = Out + (size_t)blockIdx.y * NROWS * OPI;
    const int r0 = (lane >> 4) * 4;
    #pragma unroll
    for (int n = 0; n < 4; ++n)
        #pragma unroll
        for (int r = 0; r < 4; ++r) {
            const int grow = brow + wid * 16 + r0 + r;
            if (grow < NROWS)
                outp[(size_t)grow * OPI + n * 16 + lrow] = acc[n][r];
        }
}

// ------- k_hw2: Zt8 = fp8( (relu(sum_s H[s]) @ W2)^T / 4 )  [16][N] ------
__global__ __launch_bounds__(256)
void k_hw2(const float* __restrict__ Hpart, const float* __restrict__ W2,
           unsigned char* __restrict__ Zt8, int S1) {
    __shared__ float w2[OPI * OPO];
    __shared__ float hs[16 * 68];
    const int t = threadIdx.x;
    if (t * 4 < OPI * OPO)
        *(float4*)&w2[t * 4] = *(const float4*)&W2[t * 4];

    const int r  = t >> 4;
    const int c4 = (t & 15) * 4;
    const size_t rowg = (size_t)blockIdx.x * 16 + r;   // 1250*16 == 20000

    float4 h = make_float4(0.f, 0.f, 0.f, 0.f);
    for (int s = 0; s < S1; ++s) {
        const float4 v = *(const float4*)&Hpart[((size_t)s * NROWS + rowg) * OPI + c4];
        h.x += v.x; h.y += v.y; h.z += v.z; h.w += v.w;
    }
    hs[r * 68 + c4 + 0] = fmaxf(h.x, 0.f);
    hs[r * 68 + c4 + 1] = fmaxf(h.y, 0.f);
    hs[r * 68 + c4 + 2] = fmaxf(h.z, 0.f);
    hs[r * 68 + c4 + 3] = fmaxf(h.w, 0.f);
    __syncthreads();

    const int c = t & 15;
    float z = 0.f;
    #pragma unroll 8
    for (int k = 0; k < OPI; ++k)
        z = fmaf(hs[r * 68 + k], w2[k * OPO + c], z);
    Zt8[(size_t)c * NROWS + rowg] = f2fp8(z * 0.25f);   // /4; A4 carries x4
}

// -------- k_gemm2: L[s] = fp4(A)->fp8 @ Zt8^T, tile 64x16, BK2=1024 -----
__global__ __launch_bounds__(256)
void k_gemm2(const unsigned char* __restrict__ A4,
             const unsigned char* __restrict__ Zt8,
             float* __restrict__ Out, int KC) {
    __shared__ unsigned char As[64 * BK2];    // 64 KB fp8, 16B-chunk swizzled
    __shared__ unsigned char Bs[16 * BK2];    // 16 KB
    const int t    = threadIdx.x;
    const int lane = t & 63;
    const int wid  = t >> 6;
    const int lrow = lane & 15;
    const int lk   = lane >> 4;
    const int brow    = blockIdx.x * 64;
    const int k_begin = blockIdx.y * KC;
    const int k_end   = min(NROWS, k_begin + KC);   // mult of 16

    f32x4 acc = (f32x4){0.f, 0.f, 0.f, 0.f};

    const int zcol = t >> 4;
    const int zoff = (t & 15) * 64;

    u32x2 va[16], vna[16];                    // 8B nibbles = 16 elements/row
    u32x4 vz[4],  vnz[4];

    // prologue: load tile k_begin
    {
        const int  kgA = k_begin + lane * 16;           // element index
        const bool okA = kgA < k_end;
        #pragma unroll
        for (int i = 0; i < 16; ++i) {
            const int grow = brow + wid * 16 + i;
            va[i] = (u32x2){0u, 0u};
            if (okA && grow < NROWS)
                va[i] = *(const u32x2*)(A4 + (size_t)grow * A4S + (kgA >> 1));
        }
        #pragma unroll
        for (int j = 0; j < 4; ++j) {
            const int kg = k_begin + zoff + j * 16;
            vz[j] = (u32x4){0u, 0u, 0u, 0u};
            if (kg < k_end)
                vz[j] = *(const u32x4*)(Zt8 + (size_t)zcol * NROWS + kg);
        }
    }

    for (int kt = k_begin; kt < k_end; kt += BK2) {
        // ---- expand fp4 -> fp8 and write LDS ----
        #pragma unroll
        for (int i = 0; i < 16; ++i) {
            const int r  = wid * 16 + i;
            const int c  = lane;              // 16B chunk 0..63
            const int sc = (c & ~7) | ((c & 7) ^ (r & 7));
            u32x4 ex;
            const u32x2 e0 = exp8(va[i][0]);
            const u32x2 e1 = exp8(va[i][1]);
            ex[0] = e0[0]; ex[1] = e0[1]; ex[2] = e1[0]; ex[3] = e1[1];
            *(u32x4*)&As[r * BK2 + sc * 16] = ex;
        }
        #pragma unroll
        for (int j = 0; j < 4; ++j) {
            const int c  = (zoff >> 4) + j;
            const int sc = (c & ~7) | ((c & 7) ^ (zcol & 7));
            *(u32x4*)&Bs[zcol * BK2 + sc * 16] = vz[j];
        }
        __syncthreads();

        // ---- issue next-tile loads (overlap compute) ----
        {
            const int  kgn = kt + BK2 + lane * 16;
            const bool nok = kgn < k_end;
            #pragma unroll
            for (int i = 0; i < 16; ++i) {
                const int grow = brow + wid * 16 + i;
                vna[i] = (u32x2){0u, 0u};
                if (nok && grow < NROWS)
                    vna[i] = *(const u32x2*)(A4 + (size_t)grow * A4S + (kgn >> 1));
            }
            #pragma unroll
            for (int j = 0; j < 4; ++j) {
                const int kg = kt + BK2 + zoff + j * 16;
                vnz[j] = (u32x4){0u, 0u, 0u, 0u};
                if (kg < k_end)
                    vnz[j] = *(const u32x4*)(Zt8 + (size_t)zcol * NROWS + kg);
            }
        }

        // ---- compute ----
        #pragma unroll
        for (int h = 0; h < 32; ++h) {        // 32 x K=32
            const int k0   = h * 32 + lk * 8; // lane's 8 k-bytes
            const int c    = k0 >> 4;
            const int hb   = k0 & 15;         // 0 or 8
            const int sc   = (c & ~7) | ((c & 7) ^ (lrow & 7));
            const long long a = *(const long long*)&As[(wid * 16 + lrow) * BK2 + sc * 16 + hb];
            const long long b = *(const long long*)&Bs[lrow * BK2 + sc * 16 + hb];
            acc = __builtin_amdgcn_mfma_f32_16x16x32_fp8_fp8(a, b, acc, 0, 0, 0);
        }
        __syncthreads();

        #pragma unroll
        for (int i = 0; i < 16; ++i) va[i] = vna[i];
        #pragma unroll
        for (int j = 0; j < 4; ++j)  vz[j] = vnz[j];
    }

    float* outp = Out + (size_t)blockIdx.y * NROWS * OPO;
    const int r0 = (lane >> 4) * 4;
    #pragma unroll
    for (int r = 0; r < 4; ++r) {
        const int grow = brow + wid * 16 + r0 + r;
        if (grow < NROWS) outp[(size_t)grow * OPO + lrow] = acc[r];
    }
}

// ---- k_softmax: out = softmax(sum_s Lpart[s])  (x4/÷4 scales cancel) ----
__global__ __launch_bounds__(256)
void k_softmax(const float* __restrict__ Lpart, float* __restrict__ out, int S2) {
    const int t = threadIdx.x;
    const size_t base = (size_t)blockIdx.x * 256;      // 16 rows x 16 cols
    float v = 0.f;
    for (int s = 0; s < S2; ++s)
        v += Lpart[(size_t)s * NROWS * OPO + base + t];
    float m = v;
    #pragma unroll
    for (int d = 8; d >= 1; d >>= 1) m = fmaxf(m, __shfl_xor(m, d, 16));
    const float e = expf(v - m);
    float sum = e;
    #pragma unroll
    for (int d = 8; d >= 1; d >>= 1) sum += __shfl_xor(sum, d, 16);
    out[base + t] = e / sum;
}

// ------------------------------------------------------------------------
extern "C" void kernel_launch(void* const* d_in, const int* in_sizes, int n_in,
                              void* d_out, int out_size, void* d_ws, size_t ws_size,
                              hipStream_t stream) {
    const float* A  = (const float*)d_in[0];
    const float* X  = (const float*)d_in[1];
    const float* W1 = (const float*)d_in[2];
    const float* W2 = (const float*)d_in[3];
    float* out = (float*)d_out;

    auto al = [](size_t x) { return (x + 1023) & ~(size_t)1023; };
    const size_t a4_b = al((size_t)NROWS * A4S);          // 205 MB fp4 A (padded)
    const size_t bt_b = al((size_t)OPI * NROWS * 2);
    const size_t z8_b = al((size_t)OPO * NROWS);

    int S1 = 8, S2 = 8;
    auto need = [&](int s1, int s2) {
        return a4_b + bt_b + z8_b +
               ((size_t)s1 * NROWS * OPI + (size_t)s2 * NROWS * OPO) * sizeof(float);
    };
    while ((S1 > 1 || S2 > 1) && need(S1, S2) > ws_size) {
        if (S1 > 1) S1 >>= 1;
        if (S2 > 1) S2 >>= 1;
    }

    char* p = (char*)d_ws;
    unsigned char*  A4  = (unsigned char*)p;
    unsigned short* Bt  = (unsigned short*)(p + a4_b);
    unsigned char*  Zt8 = (unsigned char*)(p + a4_b + bt_b);
    float* H = (float*)(p + a4_b + bt_b + z8_b);        // [S1][N][64]
    float* L = H + (size_t)S1 * NROWS * OPI;            // [S2][N][16]

    const int MT  = (NROWS + 63) / 64;                  // 313
    const int KC1 = ((((NROWS + S1 - 1) / S1) + BK - 1) / BK) * BK;
    const int KC2 = ((((NROWS + S2 - 1) / S2) + 511) & ~511);   // 2560

    k_xw1<<<dim3(NROWS / 16), 256, 0, stream>>>(X, W1, Bt);
    k_gemm1<<<dim3(MT, S1), 256, 0, stream>>>(A, Bt, H, A4, KC1);
    k_hw2<<<dim3(NROWS / 16), 256, 0, stream>>>(H, W2, Zt8, S1);
    k_gemm2<<<dim3(MT, S2), 256, 0, stream>>>(A4, Zt8, L, KC2);
    k_softmax<<<dim3(NROWS * OPO / 256), 256, 0, stream>>>(L, out, S2);
}